// Round 8
// baseline (429.377 us; speedup 1.0000x reference)
//
#include <hip/hip_runtime.h>

// rate_RNN_mante: T=1000 sequential scan, B=64, IN=4, H=512, OUT=3, P=2.
// Rank-2 recurrence: Wr @ r == (l*pin) @ (pout^T @ r)  -> two dot products.
// One wave per batch; lane owns 8 hidden units as 4 named v2f pairs.
// M~ = 2*log2e*mem so tanh(mem) = 1 - 2*rcp(exp2(M~)+1) (native v_exp_f32).
// SOFTWARE PIPELINE: pre_{t+1} = lm*MM_t + Win*x_{t+1} is s-independent and
// is computed INSIDE step t's DPP-reduction shadow (explicitly hoisted),
// so the 30-op DPP chain + readlane latency is covered by 16 pk_fmas.

#define T_STEPS 1000
#define BATCH   64
#define H       512
#define OUTDIM  3

typedef float v2f __attribute__((ext_vector_type(2)));

#if __has_builtin(__builtin_amdgcn_exp2f)
#define EXP2(x) __builtin_amdgcn_exp2f(x)
#else
#define EXP2(x) exp2f(x)
#endif

template<int CTRL, int RM>
__device__ __forceinline__ float dpp_add(float x) {
    int mv = __builtin_amdgcn_update_dpp(0, __builtin_bit_cast(int, x),
                                         CTRL, RM, 0xf, true);
    return x + __builtin_bit_cast(float, mv);
}

__device__ __forceinline__ float bcast63(float x) {
    return __builtin_bit_cast(float,
        __builtin_amdgcn_readlane(__builtin_bit_cast(int, x), 63));
}

__global__ __launch_bounds__(64, 1) void rnn_scan_kernel(
    const float* __restrict__ x,     // [T, B, 4, 1]
    const float* __restrict__ Win,   // [H, 4]
    const float* __restrict__ Wout,  // [3, H]
    const float* __restrict__ pin,   // [H, 2]
    const float* __restrict__ pout,  // [H, 2]
    const float* __restrict__ l,     // [2]
    float* __restrict__ out)         // [T, B, 3, 1]
{
    const int b    = blockIdx.x;
    const int lane = threadIdx.x;

    __shared__ float4 xs[T_STEPS];
    const float4* x4 = (const float4*)x;
    for (int t = lane; t < T_STEPS; t += 64)
        xs[t] = x4[t * BATCH + b];

    const float lm = 0.9048374180359595f;            // fp32(exp(-DT/TAUM))
    const float ct = 2.0f * 1.4426950408889634f * (1.0f - lm); // 2*log2e*(1-lm)
    const float l0 = l[0], l1 = l[1];

#define DECLG(G) v2f wx##G, wy##G, wz##G, ww##G, A0##G, A1##G, \
                     P0##G, P1##G, O0##G, O1##G, O2##G, MM##G;
    DECLG(0) DECLG(1) DECLG(2) DECLG(3)

#define LOADG(G, K0) do {                                                     \
    const int h0 = lane + 64 * (K0);                                          \
    const int h1 = h0 + 64;                                                   \
    float4 w0 = ((const float4*)Win)[h0];                                     \
    float4 w1 = ((const float4*)Win)[h1];                                     \
    wx##G = (v2f){ct * w0.x, ct * w1.x};                                      \
    wy##G = (v2f){ct * w0.y, ct * w1.y};                                      \
    wz##G = (v2f){ct * w0.z, ct * w1.z};                                      \
    ww##G = (v2f){ct * w0.w, ct * w1.w};                                      \
    float2 pi0 = ((const float2*)pin)[h0];                                    \
    float2 pi1 = ((const float2*)pin)[h1];                                    \
    A0##G = (v2f){ct * l0 * pi0.x, ct * l0 * pi1.x};                          \
    A1##G = (v2f){ct * l1 * pi0.y, ct * l1 * pi1.y};                          \
    float2 q0 = ((const float2*)pout)[h0];                                    \
    float2 q1 = ((const float2*)pout)[h1];                                    \
    P0##G = (v2f){q0.x, q1.x};                                                \
    P1##G = (v2f){q0.y, q1.y};                                                \
    O0##G = (v2f){Wout[0 * H + h0], Wout[0 * H + h1]};                        \
    O1##G = (v2f){Wout[1 * H + h0], Wout[1 * H + h1]};                        \
    O2##G = (v2f){Wout[2 * H + h0], Wout[2 * H + h1]};                        \
    MM##G = (v2f){0.0f, 0.0f};                                                \
} while (0)
    LOADG(0, 0); LOADG(1, 2); LOADG(2, 4); LOADG(3, 6);

    float s0 = 0.0f, s1 = 0.0f;   // pout^T tanh(mem); tanh(0) = 0
    __syncthreads();

    // ---- pipeline prologue: pre(0) from MM=0 and x(0); xB = x(1) ----
    float4 xA = xs[0];
#define PRE0(G) v2f pre##G = wx##G * xA.x + wy##G * xA.y                      \
                           + wz##G * xA.z + ww##G * xA.w;
    PRE0(0) PRE0(1) PRE0(2) PRE0(3)
    float4 xB = xs[1];

    float* outp = out + b * OUTDIM;
    for (int t = 0; t < T_STEPS; ++t) {
        // ---- body(t): s-dependent update + tanh ----
#define STEPG(G)                                                              \
        MM##G = pre##G + A1##G * s1 + A0##G * s0;                             \
        v2f r##G;                                                             \
        {                                                                     \
            float e0 = EXP2(MM##G.x);                                         \
            float e1 = EXP2(MM##G.y);                                         \
            r##G.x = fmaf(-2.0f, __builtin_amdgcn_rcpf(e0 + 1.0f), 1.0f);     \
            r##G.y = fmaf(-2.0f, __builtin_amdgcn_rcpf(e1 + 1.0f), 1.0f);     \
        }
        STEPG(0) STEPG(1) STEPG(2) STEPG(3)

        // ---- per-lane collapse, 5 outputs ----
#define ACC(NAME, W)                                                          \
        float NAME;                                                           \
        {                                                                     \
            v2f ua = W##0 * r0 + W##1 * r1;                                   \
            v2f ub = W##2 * r2 + W##3 * r3;                                   \
            v2f uc = ua + ub;                                                 \
            NAME = uc.x + uc.y;                                               \
        }
        ACC(p0, P0) ACC(p1, P1) ACC(p2, O0) ACC(p3, O1) ACC(p4, O2)

        // prefetch x(t+2) for next iteration's PREnext
        float4 xC = xs[(t + 2 < T_STEPS) ? t + 2 : 0];

        // ---- wave reduction: 5 chains interleaved, total in lane 63 ----
#define RND(CTRL, RM)                                                         \
        p0 = dpp_add<CTRL, RM>(p0); p1 = dpp_add<CTRL, RM>(p1);               \
        p2 = dpp_add<CTRL, RM>(p2); p3 = dpp_add<CTRL, RM>(p3);               \
        p4 = dpp_add<CTRL, RM>(p4);
        RND(0x111, 0xf)   // row_shr:1
        RND(0x112, 0xf)   // row_shr:2
        RND(0x114, 0xf)   // row_shr:4
        RND(0x118, 0xf)   // row_shr:8
        RND(0x142, 0xa)   // row_bcast:15 -> rows 1,3
        RND(0x143, 0xc)   // row_bcast:31 -> rows 2,3

        // ---- PREnext: s-INDEPENDENT filler for the DPP/readlane shadow ----
        // pre(t+1) = lm*MM_t + ct*(Win . x(t+1)); uses xB prefetched earlier
#define PREN(G) pre##G = MM##G * lm + wx##G * xB.x + wy##G * xB.y             \
                       + wz##G * xB.z + ww##G * xB.w;
        PREN(0) PREN(1) PREN(2) PREN(3)

        s0 = bcast63(p0);
        s1 = bcast63(p1);
        if (lane == 63) {
            float* o = outp + (size_t)t * (BATCH * OUTDIM);
            o[0] = p2; o[1] = p3; o[2] = p4;
        }
        xB = xC;
    }
}

extern "C" void kernel_launch(void* const* d_in, const int* in_sizes, int n_in,
                              void* d_out, int out_size, void* d_ws, size_t ws_size,
                              hipStream_t stream) {
    const float* x    = (const float*)d_in[0];
    const float* Win  = (const float*)d_in[1];
    const float* Wout = (const float*)d_in[2];
    const float* pin  = (const float*)d_in[3];
    const float* pout = (const float*)d_in[4];
    const float* l    = (const float*)d_in[5];
    rnn_scan_kernel<<<BATCH, 64, 0, stream>>>(x, Win, Wout, pin, pout, l,
                                              (float*)d_out);
}

// Round 9
// 410.412 us; speedup vs baseline: 1.0462x; 1.0462x over previous
//
#include <hip/hip_runtime.h>

// rate_RNN_mante: T=1000 sequential scan, B=64, IN=4, H=512, OUT=3, P=2.
// Rank-2 recurrence: Wr @ r == (l*pin) @ (pout^T @ r)  -> two dot products.
// One wave per batch; lane owns 8 hidden units as 4 v2f pairs.
// M~ = 2*log2e*mem so tanh(mem) = 1 - 2*rcp(exp2(M~)+1) (native v_exp_f32).
// KEY FIX (r9): VGPR_Count=68 < 96 floats of weight state => compiler was
// RELOADING weights from memory every iteration (L1-latency stalls on the
// scan's critical path). asm-launder each weight register once before the
// loop: opaque values can't be rematerialized-by-reload, forcing them to
// stay VGPR-resident for the whole scan.

#define T_STEPS 1000
#define BATCH   64
#define H       512
#define OUTDIM  3

typedef float v2f __attribute__((ext_vector_type(2)));

#if __has_builtin(__builtin_amdgcn_exp2f)
#define EXP2(x) __builtin_amdgcn_exp2f(x)
#else
#define EXP2(x) exp2f(x)
#endif

// Opaque-launder: forbids remat/reload of the value; forces VGPR residency.
#define KEEP(v) asm volatile("" : "+v"(v))

template<int CTRL, int RM>
__device__ __forceinline__ float dpp_add(float x) {
    int mv = __builtin_amdgcn_update_dpp(0, __builtin_bit_cast(int, x),
                                         CTRL, RM, 0xf, true);
    return x + __builtin_bit_cast(float, mv);
}

__device__ __forceinline__ float bcast63(float x) {
    return __builtin_bit_cast(float,
        __builtin_amdgcn_readlane(__builtin_bit_cast(int, x), 63));
}

__global__ __launch_bounds__(64, 1) void rnn_scan_kernel(
    const float* __restrict__ x,     // [T, B, 4, 1]
    const float* __restrict__ Win,   // [H, 4]
    const float* __restrict__ Wout,  // [3, H]
    const float* __restrict__ pin,   // [H, 2]
    const float* __restrict__ pout,  // [H, 2]
    const float* __restrict__ l,     // [2]
    float* __restrict__ out)         // [T, B, 3, 1]
{
    const int b    = blockIdx.x;
    const int lane = threadIdx.x;

    __shared__ float4 xs[T_STEPS];
    const float4* x4 = (const float4*)x;
    for (int t = lane; t < T_STEPS; t += 64)
        xs[t] = x4[t * BATCH + b];

    const float lm = 0.9048374180359595f;            // fp32(exp(-DT/TAUM))
    const float ct = 2.0f * 1.4426950408889634f * (1.0f - lm); // 2*log2e*(1-lm)
    const float l0 = l[0], l1 = l[1];

#define DECLG(G) v2f wx##G, wy##G, wz##G, ww##G, A0##G, A1##G, \
                     P0##G, P1##G, O0##G, O1##G, O2##G, MM##G;
    DECLG(0) DECLG(1) DECLG(2) DECLG(3)

#define LOADG(G, K0) do {                                                     \
    const int h0 = lane + 64 * (K0);                                          \
    const int h1 = h0 + 64;                                                   \
    float4 w0 = ((const float4*)Win)[h0];                                     \
    float4 w1 = ((const float4*)Win)[h1];                                     \
    wx##G = (v2f){ct * w0.x, ct * w1.x};                                      \
    wy##G = (v2f){ct * w0.y, ct * w1.y};                                      \
    wz##G = (v2f){ct * w0.z, ct * w1.z};                                      \
    ww##G = (v2f){ct * w0.w, ct * w1.w};                                      \
    float2 pi0 = ((const float2*)pin)[h0];                                    \
    float2 pi1 = ((const float2*)pin)[h1];                                    \
    A0##G = (v2f){ct * l0 * pi0.x, ct * l0 * pi1.x};                          \
    A1##G = (v2f){ct * l1 * pi0.y, ct * l1 * pi1.y};                          \
    float2 q0 = ((const float2*)pout)[h0];                                    \
    float2 q1 = ((const float2*)pout)[h1];                                    \
    P0##G = (v2f){q0.x, q1.x};                                                \
    P1##G = (v2f){q0.y, q1.y};                                                \
    O0##G = (v2f){Wout[0 * H + h0], Wout[0 * H + h1]};                        \
    O1##G = (v2f){Wout[1 * H + h0], Wout[1 * H + h1]};                        \
    O2##G = (v2f){Wout[2 * H + h0], Wout[2 * H + h1]};                        \
    MM##G = (v2f){0.0f, 0.0f};                                                \
} while (0)
    LOADG(0, 0); LOADG(1, 2); LOADG(2, 4); LOADG(3, 6);

    // Force all weights VGPR-resident across the scan (no remat-by-reload).
#define KEEPG(G) KEEP(wx##G); KEEP(wy##G); KEEP(wz##G); KEEP(ww##G);          \
                 KEEP(A0##G); KEEP(A1##G); KEEP(P0##G); KEEP(P1##G);          \
                 KEEP(O0##G); KEEP(O1##G); KEEP(O2##G);
    KEEPG(0) KEEPG(1) KEEPG(2) KEEPG(3)

    float s0 = 0.0f, s1 = 0.0f;   // pout^T tanh(mem); tanh(0) = 0
    __syncthreads();

    float* outp = out + b * OUTDIM;
    float4 xt = xs[0];
    for (int t = 0; t < T_STEPS; ++t) {
        // prefetch next step's input (latency hides under this step's chain)
        float4 xn = xs[(t + 1 < T_STEPS) ? t + 1 : 0];

        // s-independent prework: pre = lm*M + ct*(Win . x)
#define PREW(G) v2f pre##G = MM##G * lm + wx##G * xt.x + wy##G * xt.y          \
                           + wz##G * xt.z + ww##G * xt.w;
        PREW(0) PREW(1) PREW(2) PREW(3)

        // s-dependent: M' = pre + A1*s1 + A0*s0 ; r = tanh(mem')
#define STEPG(G)                                                              \
        MM##G = pre##G + A1##G * s1 + A0##G * s0;                             \
        v2f r##G;                                                             \
        {                                                                     \
            float e0 = EXP2(MM##G.x);                                         \
            float e1 = EXP2(MM##G.y);                                         \
            r##G.x = fmaf(-2.0f, __builtin_amdgcn_rcpf(e0 + 1.0f), 1.0f);     \
            r##G.y = fmaf(-2.0f, __builtin_amdgcn_rcpf(e1 + 1.0f), 1.0f);     \
        }
        STEPG(0) STEPG(1) STEPG(2) STEPG(3)

        // depth-2 tree accumulation, 5 outputs
#define ACC(NAME, W)                                                          \
        float NAME;                                                           \
        {                                                                     \
            v2f ua = W##0 * r0 + W##1 * r1;                                   \
            v2f ub = W##2 * r2 + W##3 * r3;                                   \
            v2f uc = ua + ub;                                                 \
            NAME = uc.x + uc.y;                                               \
        }
        ACC(p0, P0) ACC(p1, P1) ACC(p2, O0) ACC(p3, O1) ACC(p4, O2)

        // fused 5-value DPP wave-sum, chains hand-interleaved; total in lane 63
#define RND(CTRL, RM)                                                         \
        p0 = dpp_add<CTRL, RM>(p0); p1 = dpp_add<CTRL, RM>(p1);               \
        p2 = dpp_add<CTRL, RM>(p2); p3 = dpp_add<CTRL, RM>(p3);               \
        p4 = dpp_add<CTRL, RM>(p4);
        RND(0x111, 0xf)   // row_shr:1
        RND(0x112, 0xf)   // row_shr:2
        RND(0x114, 0xf)   // row_shr:4
        RND(0x118, 0xf)   // row_shr:8
        RND(0x142, 0xa)   // row_bcast:15 -> rows 1,3
        RND(0x143, 0xc)   // row_bcast:31 -> rows 2,3

        s0 = bcast63(p0);
        s1 = bcast63(p1);
        if (lane == 63) {
            float* o = outp + (size_t)t * (BATCH * OUTDIM);
            o[0] = p2; o[1] = p3; o[2] = p4;
        }
        xt = xn;
    }
}

extern "C" void kernel_launch(void* const* d_in, const int* in_sizes, int n_in,
                              void* d_out, int out_size, void* d_ws, size_t ws_size,
                              hipStream_t stream) {
    const float* x    = (const float*)d_in[0];
    const float* Win  = (const float*)d_in[1];
    const float* Wout = (const float*)d_in[2];
    const float* pin  = (const float*)d_in[3];
    const float* pout = (const float*)d_in[4];
    const float* l    = (const float*)d_in[5];
    rnn_scan_kernel<<<BATCH, 64, 0, stream>>>(x, Win, Wout, pin, pout, l,
                                              (float*)d_out);
}

// Round 10
// 323.852 us; speedup vs baseline: 1.3258x; 1.2673x over previous
//
#include <hip/hip_runtime.h>

// rate_RNN_mante: T=1000 serial scan, B=64, IN=4, H=512, OUT=3, P=2.
// Rank-2 recurrence: only s_p = pout[:,p]^T tanh(mem) (2 scalars) is serial.
// RESTRUCTURE (r10): pass 1 = serial scan, 2 reduction chains only, streams
// r=tanh(mem) to workspace (coalesced, fire-and-forget). pass 2 = massively
// parallel GEMV y = Wout . r (latency hidden by occupancy). Removes the 3
// y-ACC trees + 18 DPP ops + divergent store + 24 Wout regs from the
// latency-exposed serial loop. ws_size-dispatch: fp32 ws / bf16 ws / fused
// fallback (round-7 kernel) so any workspace size stays correct.

#define T_STEPS 1000
#define BATCH   64
#define H       512
#define OUTDIM  3

typedef float v2f __attribute__((ext_vector_type(2)));

#if __has_builtin(__builtin_amdgcn_exp2f)
#define EXP2(x) __builtin_amdgcn_exp2f(x)
#else
#define EXP2(x) exp2f(x)
#endif

template<int CTRL, int RM>
__device__ __forceinline__ float dpp_add(float x) {
    int mv = __builtin_amdgcn_update_dpp(0, __builtin_bit_cast(int, x),
                                         CTRL, RM, 0xf, true);
    return x + __builtin_bit_cast(float, mv);
}

__device__ __forceinline__ float bcast63(float x) {
    return __builtin_bit_cast(float,
        __builtin_amdgcn_readlane(__builtin_bit_cast(int, x), 63));
}

// ---------------------------------------------------------------------------
// Pass 1: serial scan. Lane owns h = 8*lane..8*lane+7 (contiguous, so the
// r-store is two/one coalesced wide stores). MODE 0: fp32 r_ws, 1: bf16 r_ws.
// ---------------------------------------------------------------------------
template<int MODE>
__global__ __launch_bounds__(64, 1) void rnn_scan_store(
    const float* __restrict__ x,     // [T, B, 4, 1]
    const float* __restrict__ Win,   // [H, 4]
    const float* __restrict__ pin,   // [H, 2]
    const float* __restrict__ pout,  // [H, 2]
    const float* __restrict__ l,     // [2]
    void* __restrict__ r_ws)         // [T, B, H] fp32 or bf16
{
    const int b    = blockIdx.x;
    const int lane = threadIdx.x;

    __shared__ float4 xs[T_STEPS];
    const float4* x4 = (const float4*)x;
    for (int t = lane; t < T_STEPS; t += 64)
        xs[t] = x4[t * BATCH + b];

    const float lm = 0.9048374180359595f;            // fp32(exp(-DT/TAUM))
    const float ct = 2.0f * 1.4426950408889634f * (1.0f - lm); // 2*log2e*(1-lm)
    const float l0 = l[0], l1 = l[1];
    const int hb = 8 * lane;                         // contiguous ownership

#define SDECLG(G) v2f wx##G, wy##G, wz##G, ww##G, A0##G, A1##G, \
                      P0##G, P1##G, MM##G;
    SDECLG(0) SDECLG(1) SDECLG(2) SDECLG(3)

#define SLOADG(G) do {                                                        \
    const int h0 = hb + 2 * G;                                                \
    const int h1 = h0 + 1;                                                    \
    float4 w0 = ((const float4*)Win)[h0];                                     \
    float4 w1 = ((const float4*)Win)[h1];                                     \
    wx##G = (v2f){ct * w0.x, ct * w1.x};                                      \
    wy##G = (v2f){ct * w0.y, ct * w1.y};                                      \
    wz##G = (v2f){ct * w0.z, ct * w1.z};                                      \
    ww##G = (v2f){ct * w0.w, ct * w1.w};                                      \
    float2 pi0 = ((const float2*)pin)[h0];                                    \
    float2 pi1 = ((const float2*)pin)[h1];                                    \
    A0##G = (v2f){ct * l0 * pi0.x, ct * l0 * pi1.x};                          \
    A1##G = (v2f){ct * l1 * pi0.y, ct * l1 * pi1.y};                          \
    float2 q0 = ((const float2*)pout)[h0];                                    \
    float2 q1 = ((const float2*)pout)[h1];                                    \
    P0##G = (v2f){q0.x, q1.x};                                                \
    P1##G = (v2f){q0.y, q1.y};                                                \
    MM##G = (v2f){0.0f, 0.0f};                                                \
} while (0)
    SLOADG(0); SLOADG(1); SLOADG(2); SLOADG(3);

    float s0 = 0.0f, s1 = 0.0f;   // pout^T tanh(mem); tanh(0) = 0
    __syncthreads();

    // per-step output pointer, strength-reduced
    const size_t esz  = (MODE == 0) ? 4 : 2;
    char* rptr = (char*)r_ws + ((size_t)b * H + hb) * esz;
    const size_t rstep = (size_t)BATCH * H * esz;

    float4 xt = xs[0];
    for (int t = 0; t < T_STEPS; ++t) {
        float4 xn = xs[(t + 1 < T_STEPS) ? t + 1 : 0];

        // s-independent prework: pre = lm*M + ct*(Win . x)
#define SPREW(G) v2f pre##G = MM##G * lm + wx##G * xt.x + wy##G * xt.y        \
                            + wz##G * xt.z + ww##G * xt.w;
        SPREW(0) SPREW(1) SPREW(2) SPREW(3)

        // s-dependent: M' = pre + A1*s1 + A0*s0 ; r = tanh(mem')
#define SSTEPG(G)                                                             \
        MM##G = pre##G + A1##G * s1 + A0##G * s0;                             \
        v2f r##G;                                                             \
        {                                                                     \
            float e0 = EXP2(MM##G.x);                                         \
            float e1 = EXP2(MM##G.y);                                         \
            r##G.x = fmaf(-2.0f, __builtin_amdgcn_rcpf(e0 + 1.0f), 1.0f);     \
            r##G.y = fmaf(-2.0f, __builtin_amdgcn_rcpf(e1 + 1.0f), 1.0f);     \
        }
        SSTEPG(0) SSTEPG(1) SSTEPG(2) SSTEPG(3)

        // stream r to workspace — fire-and-forget, coalesced (lane-contiguous)
        if (MODE == 0) {
            v2f* rp = (v2f*)rptr;
            rp[0] = r0; rp[1] = r1; rp[2] = r2; rp[3] = r3;
        } else {
            unsigned u0, u1, u2, u3;
            asm("v_cvt_pk_bf16_f32 %0, %1, %2" : "=v"(u0) : "v"(r0.x), "v"(r0.y));
            asm("v_cvt_pk_bf16_f32 %0, %1, %2" : "=v"(u1) : "v"(r1.x), "v"(r1.y));
            asm("v_cvt_pk_bf16_f32 %0, %1, %2" : "=v"(u2) : "v"(r2.x), "v"(r2.y));
            asm("v_cvt_pk_bf16_f32 %0, %1, %2" : "=v"(u3) : "v"(r3.x), "v"(r3.y));
            uint4 uu = {u0, u1, u2, u3};
            *(uint4*)rptr = uu;
        }
        rptr += rstep;

        // per-lane collapse for the 2 recurrent dots only
#define SACC(NAME, W)                                                         \
        float NAME;                                                           \
        {                                                                     \
            v2f ua = W##0 * r0 + W##1 * r1;                                   \
            v2f ub = W##2 * r2 + W##3 * r3;                                   \
            v2f uc = ua + ub;                                                 \
            NAME = uc.x + uc.y;                                               \
        }
        SACC(p0, P0) SACC(p1, P1)

        // 2-chain interleaved DPP wave-sum; totals in lane 63
#define SRND(CTRL, RM)                                                        \
        p0 = dpp_add<CTRL, RM>(p0); p1 = dpp_add<CTRL, RM>(p1);
        SRND(0x111, 0xf)   // row_shr:1
        SRND(0x112, 0xf)   // row_shr:2
        SRND(0x114, 0xf)   // row_shr:4
        SRND(0x118, 0xf)   // row_shr:8
        SRND(0x142, 0xa)   // row_bcast:15 -> rows 1,3
        SRND(0x143, 0xc)   // row_bcast:31 -> rows 2,3

        s0 = bcast63(p0);
        s1 = bcast63(p1);
        xt = xn;
    }
}

// ---------------------------------------------------------------------------
// Pass 2: y[row, o] = sum_h Wout[o,h] * r[row, h], row = t*B+b (64000 rows).
// One wave per row, 4 rows per 256-thread block. Fully parallel.
// ---------------------------------------------------------------------------
template<int MODE>
__global__ __launch_bounds__(256) void wout_gemv(
    const void* __restrict__ r_ws,   // [T*B, H]
    const float* __restrict__ Wout,  // [3, H]
    float* __restrict__ out)         // [T*B, 3]
{
    const int row  = blockIdx.x * 4 + (threadIdx.x >> 6);
    const int lane = threadIdx.x & 63;
    const int hb   = 8 * lane;

    v2f ra0, ra1, ra2, ra3;
    if (MODE == 0) {
        const v2f* rp = (const v2f*)((const float*)r_ws + (size_t)row * H + hb);
        ra0 = rp[0]; ra1 = rp[1]; ra2 = rp[2]; ra3 = rp[3];
    } else {
        uint4 u = *(const uint4*)((const unsigned short*)r_ws + (size_t)row * H + hb);
#define UNPK(U) (v2f){__builtin_bit_cast(float, (U) << 16),                   \
                      __builtin_bit_cast(float, (U) & 0xffff0000u)}
        ra0 = UNPK(u.x); ra1 = UNPK(u.y); ra2 = UNPK(u.z); ra3 = UNPK(u.w);
    }

#define GDOT(NAME, O)                                                         \
    float NAME;                                                               \
    {                                                                         \
        const v2f* wp = (const v2f*)(Wout + (O) * H + hb);                    \
        v2f ua = wp[0] * ra0 + wp[1] * ra1;                                   \
        v2f ub = wp[2] * ra2 + wp[3] * ra3;                                   \
        v2f uc = ua + ub;                                                     \
        NAME = uc.x + uc.y;                                                   \
    }
    GDOT(p0, 0) GDOT(p1, 1) GDOT(p2, 2)

#define GRND(CTRL, RM)                                                        \
    p0 = dpp_add<CTRL, RM>(p0); p1 = dpp_add<CTRL, RM>(p1);                   \
    p2 = dpp_add<CTRL, RM>(p2);
    GRND(0x111, 0xf) GRND(0x112, 0xf) GRND(0x114, 0xf)
    GRND(0x118, 0xf) GRND(0x142, 0xa) GRND(0x143, 0xc)

    if (lane == 63) {
        float* o = out + (size_t)row * OUTDIM;
        o[0] = p0; o[1] = p1; o[2] = p2;
    }
}

// ---------------------------------------------------------------------------
// Fallback: round-7 fused kernel (used only if ws_size is too small).
// ---------------------------------------------------------------------------
__global__ __launch_bounds__(64, 1) void rnn_scan_fused(
    const float* __restrict__ x, const float* __restrict__ Win,
    const float* __restrict__ Wout, const float* __restrict__ pin,
    const float* __restrict__ pout, const float* __restrict__ l,
    float* __restrict__ out)
{
    const int b    = blockIdx.x;
    const int lane = threadIdx.x;

    __shared__ float4 xs[T_STEPS];
    const float4* x4 = (const float4*)x;
    for (int t = lane; t < T_STEPS; t += 64)
        xs[t] = x4[t * BATCH + b];

    const float lm = 0.9048374180359595f;
    const float ct = 2.0f * 1.4426950408889634f * (1.0f - lm);
    const float l0 = l[0], l1 = l[1];

#define FDECLG(G) v2f fwx##G, fwy##G, fwz##G, fww##G, fA0##G, fA1##G,         \
                      fP0##G, fP1##G, fO0##G, fO1##G, fO2##G, fMM##G;
    FDECLG(0) FDECLG(1) FDECLG(2) FDECLG(3)

#define FLOADG(G, K0) do {                                                    \
    const int h0 = lane + 64 * (K0);                                          \
    const int h1 = h0 + 64;                                                   \
    float4 w0 = ((const float4*)Win)[h0];                                     \
    float4 w1 = ((const float4*)Win)[h1];                                     \
    fwx##G = (v2f){ct * w0.x, ct * w1.x};                                     \
    fwy##G = (v2f){ct * w0.y, ct * w1.y};                                     \
    fwz##G = (v2f){ct * w0.z, ct * w1.z};                                     \
    fww##G = (v2f){ct * w0.w, ct * w1.w};                                     \
    float2 pi0 = ((const float2*)pin)[h0];                                    \
    float2 pi1 = ((const float2*)pin)[h1];                                    \
    fA0##G = (v2f){ct * l0 * pi0.x, ct * l0 * pi1.x};                         \
    fA1##G = (v2f){ct * l1 * pi0.y, ct * l1 * pi1.y};                         \
    float2 q0 = ((const float2*)pout)[h0];                                    \
    float2 q1 = ((const float2*)pout)[h1];                                    \
    fP0##G = (v2f){q0.x, q1.x};                                               \
    fP1##G = (v2f){q0.y, q1.y};                                               \
    fO0##G = (v2f){Wout[0 * H + h0], Wout[0 * H + h1]};                       \
    fO1##G = (v2f){Wout[1 * H + h0], Wout[1 * H + h1]};                       \
    fO2##G = (v2f){Wout[2 * H + h0], Wout[2 * H + h1]};                       \
    fMM##G = (v2f){0.0f, 0.0f};                                               \
} while (0)
    FLOADG(0, 0); FLOADG(1, 2); FLOADG(2, 4); FLOADG(3, 6);

    float s0 = 0.0f, s1 = 0.0f;
    __syncthreads();

    float* outp = out + b * OUTDIM;
    float4 xt = xs[0];
    for (int t = 0; t < T_STEPS; ++t) {
        float4 xn = xs[(t + 1 < T_STEPS) ? t + 1 : 0];
#define FPREW(G) v2f pre##G = fMM##G * lm + fwx##G * xt.x + fwy##G * xt.y     \
                            + fwz##G * xt.z + fww##G * xt.w;
        FPREW(0) FPREW(1) FPREW(2) FPREW(3)
#define FSTEPG(G)                                                             \
        fMM##G = pre##G + fA1##G * s1 + fA0##G * s0;                          \
        v2f r##G;                                                             \
        {                                                                     \
            float e0 = EXP2(fMM##G.x);                                        \
            float e1 = EXP2(fMM##G.y);                                        \
            r##G.x = fmaf(-2.0f, __builtin_amdgcn_rcpf(e0 + 1.0f), 1.0f);     \
            r##G.y = fmaf(-2.0f, __builtin_amdgcn_rcpf(e1 + 1.0f), 1.0f);     \
        }
        FSTEPG(0) FSTEPG(1) FSTEPG(2) FSTEPG(3)
#define FACC(NAME, W)                                                         \
        float NAME;                                                           \
        {                                                                     \
            v2f ua = W##0 * r0 + W##1 * r1;                                   \
            v2f ub = W##2 * r2 + W##3 * r3;                                   \
            v2f uc = ua + ub;                                                 \
            NAME = uc.x + uc.y;                                               \
        }
        FACC(p0, fP0) FACC(p1, fP1) FACC(p2, fO0) FACC(p3, fO1) FACC(p4, fO2)
#define FRND(CTRL, RM)                                                        \
        p0 = dpp_add<CTRL, RM>(p0); p1 = dpp_add<CTRL, RM>(p1);               \
        p2 = dpp_add<CTRL, RM>(p2); p3 = dpp_add<CTRL, RM>(p3);               \
        p4 = dpp_add<CTRL, RM>(p4);
        FRND(0x111, 0xf) FRND(0x112, 0xf) FRND(0x114, 0xf)
        FRND(0x118, 0xf) FRND(0x142, 0xa) FRND(0x143, 0xc)
        s0 = bcast63(p0);
        s1 = bcast63(p1);
        if (lane == 63) {
            float* o = outp + (size_t)t * (BATCH * OUTDIM);
            o[0] = p2; o[1] = p3; o[2] = p4;
        }
        xt = xn;
    }
}

extern "C" void kernel_launch(void* const* d_in, const int* in_sizes, int n_in,
                              void* d_out, int out_size, void* d_ws, size_t ws_size,
                              hipStream_t stream) {
    const float* x    = (const float*)d_in[0];
    const float* Win  = (const float*)d_in[1];
    const float* Wout = (const float*)d_in[2];
    const float* pin  = (const float*)d_in[3];
    const float* pout = (const float*)d_in[4];
    const float* l    = (const float*)d_in[5];
    float* out = (float*)d_out;

    const size_t need_f32  = (size_t)T_STEPS * BATCH * H * sizeof(float);
    const size_t need_bf16 = (size_t)T_STEPS * BATCH * H * sizeof(unsigned short);
    const int gemv_grid = (T_STEPS * BATCH) / 4;   // 4 rows (waves) per block

    if (ws_size >= need_f32) {
        rnn_scan_store<0><<<BATCH, 64, 0, stream>>>(x, Win, pin, pout, l, d_ws);
        wout_gemv<0><<<gemv_grid, 256, 0, stream>>>(d_ws, Wout, out);
    } else if (ws_size >= need_bf16) {
        rnn_scan_store<1><<<BATCH, 64, 0, stream>>>(x, Win, pin, pout, l, d_ws);
        wout_gemv<1><<<gemv_grid, 256, 0, stream>>>(d_ws, Wout, out);
    } else {
        rnn_scan_fused<<<BATCH, 64, 0, stream>>>(x, Win, Wout, pin, pout, l, out);
    }
}